// Round 1
// baseline (927.761 us; speedup 1.0000x reference)
//
#include <hip/hip_runtime.h>

// ---------------------------------------------------------------------------
// Two stacked SwinV2 shifted-window attentions, MI355X/gfx950.
// Pipeline: t_in (NCHW->NHWC) -> [k_swin (attn+proj fused)] x2 -> t_out.
// k_setup converts weights to bf16 and precomputes 16*sigmoid(cpb MLP) tables.
// Fusion note: proj is per-token and the window partition is disjoint, so the
// proj GEMM is block-local. The block writes its AO tile (32 KB) to global,
// __syncthreads() (drains vmcnt, L1 is write-through/invalidate on CDNA)
// makes it visible within the block, then re-reads it L2-hot for the proj.
// ---------------------------------------------------------------------------

typedef short bf16x8 __attribute__((ext_vector_type(8)));
typedef float f32x4 __attribute__((ext_vector_type(4)));

__device__ __forceinline__ unsigned short f2bf(float f) {
    union { float f; unsigned int u; } v; v.f = f;
    return (unsigned short)((v.u + 0x7fffu + ((v.u >> 16) & 1u)) >> 16);
}
__device__ __forceinline__ float bf2f(unsigned short b) {
    union { unsigned int u; float f; } v; v.u = ((unsigned int)b) << 16;
    return v.f;
}
__device__ __forceinline__ f32x4 mfma_bf16(bf16x8 a, bf16x8 b, f32x4 c) {
    return __builtin_amdgcn_mfma_f32_16x16x32_bf16(a, b, c, 0, 0, 0);
}

// region id for the swin shifted mask (pH=pW=64, ws=8, shift=4).
__device__ __forceinline__ int region_of(int wh, int ww, int t) {
    int th = t >> 3, tw = t & 7;
    int rh = (wh == 7) ? ((th < 4) ? 1 : 2) : 0;
    int rw = (ww == 7) ? ((tw < 4) ? 1 : 2) : 0;
    return rh * 3 + rw;
}

// ---------------------------------------------------------------------------
// setup: blocks 0..511 convert weights f32->bf16; blocks 512/513 compute the
// continuous-relative-position-bias tables (already through 16*sigmoid).
// ---------------------------------------------------------------------------
__global__ __launch_bounds__(256) void k_setup(
    const float* __restrict__ qkvw1, const float* __restrict__ projw1,
    const float* __restrict__ qkvw2, const float* __restrict__ projw2,
    const float* __restrict__ w1a, const float* __restrict__ b1a, const float* __restrict__ w2a,
    const float* __restrict__ w1b, const float* __restrict__ b1b, const float* __restrict__ w2b,
    unsigned short* __restrict__ qw1, unsigned short* __restrict__ pw1,
    unsigned short* __restrict__ qw2, unsigned short* __restrict__ pw2,
    float* __restrict__ bt1, float* __restrict__ bt2)
{
    int b = blockIdx.x, t = threadIdx.x;
    if (b < 512) {
        int idx = b * 256 + t;
        #pragma unroll
        for (int r = 0; r < 4; r++) {
            int i = idx + r * 131072;
            if (i < 196608)        qw1[i]          = f2bf(qkvw1[i]);
            else if (i < 262144)   pw1[i - 196608] = f2bf(projw1[i - 196608]);
            else if (i < 458752)   qw2[i - 262144] = f2bf(qkvw2[i - 262144]);
            else                   pw2[i - 458752] = f2bf(projw2[i - 458752]);
        }
    } else {
        int a = b - 512;
        const float* w1 = a ? w1b : w1a;
        const float* b1 = a ? b1b : b1a;
        const float* w2 = a ? w2b : w2a;
        float* out = a ? bt2 : bt1;
        int k = t;
        if (k >= 225) return;
        int ih = k / 15, iw = k % 15;
        float v0 = (float)(ih - 7) / 7.0f * 8.0f;
        float v1 = (float)(iw - 7) / 7.0f * 8.0f;
        float t0 = (v0 >= 0.f ? 1.f : -1.f) * log2f(fabsf(v0) + 1.f) / 3.0f;
        float t1 = (v1 >= 0.f ? 1.f : -1.f) * log2f(fabsf(v1) + 1.f) / 3.0f;
        float acc[8] = {0.f, 0.f, 0.f, 0.f, 0.f, 0.f, 0.f, 0.f};
        for (int c = 0; c < 512; c++) {
            float hc = t0 * w1[2 * c] + t1 * w1[2 * c + 1] + b1[c];
            hc = fmaxf(hc, 0.f);
            #pragma unroll
            for (int h = 0; h < 8; h++) acc[h] += hc * w2[h * 512 + c];
        }
        #pragma unroll
        for (int h = 0; h < 8; h++) out[k * 8 + h] = 16.f / (1.f + expf(-acc[h]));
    }
}

// ---------------------------------------------------------------------------
// transposes: src [32][256][4096] <-> NHWC [32][4096][256]
// ---------------------------------------------------------------------------
__global__ __launch_bounds__(256) void t_in(const float* __restrict__ src, float* __restrict__ dst) {
    __shared__ float tile[32][33];
    int img = blockIdx.z, hw0 = blockIdx.x * 32, c0 = blockIdx.y * 32;
    int x = threadIdx.x & 31, y = threadIdx.x >> 5;
    #pragma unroll
    for (int k = 0; k < 4; k++)
        tile[y + k * 8][x] = src[((size_t)img * 256 + c0 + y + k * 8) * 4096 + hw0 + x];
    __syncthreads();
    #pragma unroll
    for (int k = 0; k < 4; k++)
        dst[((size_t)img * 4096 + hw0 + y + k * 8) * 256 + c0 + x] = tile[x][y + k * 8];
}

__global__ __launch_bounds__(256) void t_out(const float* __restrict__ src, float* __restrict__ dst) {
    __shared__ float tile[32][33];
    int img = blockIdx.z, hw0 = blockIdx.x * 32, c0 = blockIdx.y * 32;
    int x = threadIdx.x & 31, y = threadIdx.x >> 5;
    #pragma unroll
    for (int k = 0; k < 4; k++)
        tile[y + k * 8][x] = src[((size_t)img * 4096 + hw0 + y + k * 8) * 256 + c0 + x];
    __syncthreads();
    #pragma unroll
    for (int k = 0; k < 4; k++)
        dst[((size_t)img * 256 + c0 + y + k * 8) * 4096 + hw0 + x] = tile[x][y + k * 8];
}

// ---------------------------------------------------------------------------
// k_swin: one block per window (2048 blocks, 256 thr = 4 waves).
// Phase A (attention): loops over 4 head-pairs: QKV GEMM (64x192, K=256) ->
// norms/Vt -> per head: S = Qn Kn^T * scale + bias (+mask) -> softmax -> P V
// -> AO (bf16, global, block-local).
// Phase B (projection): re-stage own AO tile (L2-hot), out = AO @ Wp^T + bp
// + residual, scattered back to NHWC f32 with the roll-back folded in.
// ---------------------------------------------------------------------------
__global__ __launch_bounds__(256, 2) void k_swin(
    const float* __restrict__ Xin,           // NHWC f32 [32][64][64][256] (also residual)
    const unsigned short* __restrict__ Wq,   // qkv_w bf16 [768][256]
    const float* __restrict__ bq,            // qkv_b f32 [768] (k part zeroed here)
    const float* __restrict__ lsc,           // logit_scale [8]
    const float* __restrict__ btab,          // 16*sigmoid(bias) f32 [225*8]
    const unsigned short* __restrict__ Wp,   // proj_w bf16 [256][256]
    const float* __restrict__ bp,            // proj_b [256]
    unsigned short* __restrict__ AO,         // attn_out bf16 [2048][64][256] (scratch)
    float* __restrict__ Xout,                // output NHWC f32
    int shift, int masked)
{
    __shared__ __align__(16) unsigned short sX[64 * 264];    // X window bf16; reused as O in phase B
    __shared__ __align__(16) unsigned short sQKV[64 * 200];  // q0 q1 k0 k1 v0 v1 (32 each)
    __shared__ __align__(16) unsigned short sP[64 * 72];     // softmax probs bf16
    __shared__ __align__(16) unsigned short sVt[64 * 72];    // V transposed [dim][token]
    __shared__ float sInv[4 * 64];                           // 1/norm for q0,q1,k0,k1

    const int tid = threadIdx.x;
    const int wv = tid >> 6, lane = tid & 63, quad = lane >> 4, nn = lane & 15;
    const int win = blockIdx.x;
    const int bt = win >> 6, wh = (win >> 3) & 7, ww = win & 7;
    const f32x4 zero4 = {0.f, 0.f, 0.f, 0.f};

    // ---- stage X window (with shift roll folded into the gather) ----
    {
        int tok = tid >> 2, part = tid & 3;
        int h = (wh * 8 + (tok >> 3) + shift) & 63;
        int w = (ww * 8 + (tok & 7) + shift) & 63;
        const float* srcp = Xin + ((size_t)(bt * 4096 + h * 64 + w)) * 256 + part * 64;
        unsigned short* dstp = sX + tok * 264 + part * 64;
        #pragma unroll
        for (int c = 0; c < 64; c += 4) {
            float4 v = *(const float4*)(srcp + c);
            unsigned int p0 = (unsigned int)f2bf(v.x) | ((unsigned int)f2bf(v.y) << 16);
            unsigned int p1 = (unsigned int)f2bf(v.z) | ((unsigned int)f2bf(v.w) << 16);
            uint2 o; o.x = p0; o.y = p1;
            *(uint2*)(dstp + c) = o;
        }
    }
    __syncthreads();

    // ======================= Phase A: attention =======================
    for (int p = 0; p < 4; p++) {
        // ===== QKV GEMM for heads (2p, 2p+1): D[64][192] = Xw @ Wsel^T + b =====
        f32x4 acc[4][3];
        #pragma unroll
        for (int rt = 0; rt < 4; rt++)
            #pragma unroll
            for (int c = 0; c < 3; c++) acc[rt][c] = zero4;

        int wrow[3], cbase[3], kindv[3];
        #pragma unroll
        for (int c = 0; c < 3; c++) {
            int ct = wv * 3 + c;           // 12 col-tiles, wave-disjoint (no L2 redundancy)
            int sec = ct >> 1;             // 0..5 : q0 q1 k0 k1 v0 v1
            int kind = sec >> 1;           // 0=q 1=k 2=v
            int head = 2 * p + (sec & 1);
            wrow[c] = kind * 256 + head * 32 + (ct & 1) * 16 + nn;  // W row = qkv channel
            cbase[c] = ct * 16 + nn;
            kindv[c] = kind;
        }
        #pragma unroll
        for (int ks = 0; ks < 8; ks++) {
            bf16x8 a[4], b[3];
            #pragma unroll
            for (int rt = 0; rt < 4; rt++)
                a[rt] = *(const bf16x8*)(sX + (rt * 16 + nn) * 264 + ks * 32 + quad * 8);
            #pragma unroll
            for (int c = 0; c < 3; c++)
                b[c] = *(const bf16x8*)(Wq + (size_t)wrow[c] * 256 + ks * 32 + quad * 8);
            #pragma unroll
            for (int rt = 0; rt < 4; rt++)
                #pragma unroll
                for (int c = 0; c < 3; c++)
                    acc[rt][c] = mfma_bf16(a[rt], b[c], acc[rt][c]);
        }
        #pragma unroll
        for (int c = 0; c < 3; c++) {
            float bias = (kindv[c] == 1) ? 0.f : bq[wrow[c]];  // v2 zeroes key bias
            #pragma unroll
            for (int rt = 0; rt < 4; rt++)
                #pragma unroll
                for (int r = 0; r < 4; r++) {
                    int tokr = rt * 16 + quad * 4 + r;
                    sQKV[tokr * 200 + cbase[c]] = f2bf(acc[rt][c][r] + bias);
                }
        }
        __syncthreads();

        // ===== per-token inverse norms (q0,q1,k0,k1) + V transpose =====
        {
            int t = tid & 63, which = tid >> 6;
            const unsigned short* row = sQKV + t * 200 + which * 32;
            float ss = 0.f;
            #pragma unroll
            for (int cc = 0; cc < 32; cc++) { float v = bf2f(row[cc]); ss += v * v; }
            sInv[which * 64 + t] = 1.f / fmaxf(sqrtf(ss), 1e-12f);
            #pragma unroll
            for (int dd = 0; dd < 16; dd++) {
                int d = which * 16 + dd;
                sVt[d * 72 + t] = sQKV[t * 200 + 128 + d];
            }
        }
        __syncthreads();

        for (int hh = 0; hh < 2; hh++) {
            const int head = 2 * p + hh;
            const float scale = __expf(fminf(lsc[head], 4.605170185988092f)); // ln(100)

            // ----- S = Q K^T (wave wv owns rows wv*16..wv*16+15) -----
            bf16x8 aq = *(const bf16x8*)(sQKV + (wv * 16 + nn) * 200 + hh * 32 + quad * 8);
            f32x4 S[4];
            #pragma unroll
            for (int ct = 0; ct < 4; ct++) {
                bf16x8 bk = *(const bf16x8*)(sQKV + (ct * 16 + nn) * 200 + 64 + hh * 32 + quad * 8);
                S[ct] = mfma_bf16(aq, bk, zero4);
            }

            const float* invq = sInv + hh * 64;
            const float* invk = sInv + (2 + hh) * 64;
            const int i_base = wv * 16 + quad * 4;
            float rowm[4] = {-3.0e38f, -3.0e38f, -3.0e38f, -3.0e38f};
            int ri[4];
            #pragma unroll
            for (int r = 0; r < 4; r++) ri[r] = masked ? region_of(wh, ww, i_base + r) : 0;

            #pragma unroll
            for (int ct = 0; ct < 4; ct++) {
                int j = ct * 16 + nn;
                float ivk = invk[j];
                int rj = masked ? region_of(wh, ww, j) : 0;
                #pragma unroll
                for (int r = 0; r < 4; r++) {
                    int i = i_base + r;
                    float v = S[ct][r] * invq[i] * ivk * scale;
                    int rel = ((i >> 3) - (j >> 3) + 7) * 15 + ((i & 7) - (j & 7) + 7);
                    v += btab[rel * 8 + head];
                    if (masked && (ri[r] != rj)) v += -100.f;
                    S[ct][r] = v;
                    rowm[r] = fmaxf(rowm[r], v);
                }
            }
            // row max / sum across the 16 lanes of each quad
            #pragma unroll
            for (int r = 0; r < 4; r++) {
                float m = rowm[r];
                m = fmaxf(m, __shfl_xor(m, 1));
                m = fmaxf(m, __shfl_xor(m, 2));
                m = fmaxf(m, __shfl_xor(m, 4));
                m = fmaxf(m, __shfl_xor(m, 8));
                rowm[r] = m;
            }
            float rsum[4] = {0.f, 0.f, 0.f, 0.f};
            #pragma unroll
            for (int ct = 0; ct < 4; ct++)
                #pragma unroll
                for (int r = 0; r < 4; r++) {
                    float e = __expf(S[ct][r] - rowm[r]);
                    S[ct][r] = e;
                    rsum[r] += e;
                }
            #pragma unroll
            for (int r = 0; r < 4; r++) {
                float s = rsum[r];
                s += __shfl_xor(s, 1);
                s += __shfl_xor(s, 2);
                s += __shfl_xor(s, 4);
                s += __shfl_xor(s, 8);
                rsum[r] = 1.f / s;
            }
            // write P (wave-private rows -> no barrier needed before PV)
            #pragma unroll
            for (int ct = 0; ct < 4; ct++)
                #pragma unroll
                for (int r = 0; r < 4; r++)
                    sP[(i_base + r) * 72 + ct * 16 + nn] = f2bf(S[ct][r] * rsum[r]);

            // ----- O = P V  (K=64 -> 2 ksteps; 2 col tiles of 16 dims) -----
            bf16x8 ap0 = *(const bf16x8*)(sP + (wv * 16 + nn) * 72 + quad * 8);
            bf16x8 ap1 = *(const bf16x8*)(sP + (wv * 16 + nn) * 72 + 32 + quad * 8);
            #pragma unroll
            for (int ct2 = 0; ct2 < 2; ct2++) {
                bf16x8 bv0 = *(const bf16x8*)(sVt + (hh * 32 + ct2 * 16 + nn) * 72 + quad * 8);
                bf16x8 bv1 = *(const bf16x8*)(sVt + (hh * 32 + ct2 * 16 + nn) * 72 + 32 + quad * 8);
                f32x4 O = mfma_bf16(ap0, bv0, zero4);
                O = mfma_bf16(ap1, bv1, O);
                #pragma unroll
                for (int r = 0; r < 4; r++) {
                    int tokr = i_base + r;
                    AO[((size_t)win * 64 + tokr) * 256 + head * 32 + ct2 * 16 + nn] = f2bf(O[r]);
                }
            }
        }
        __syncthreads();  // protect sQKV/sVt before next pair overwrites; also
                          // drains AO stores (vmcnt(0)) -> visible to the block
    }

    // ======================= Phase B: projection =======================
    // Re-stage this block's own AO tile (just written -> L2-hot) into sX.
    {
        int tok = tid >> 2, part = tid & 3;
        const unsigned short* srcp = AO + ((size_t)win * 64 + tok) * 256 + part * 64;
        unsigned short* dstp = sX + tok * 264 + part * 64;
        #pragma unroll
        for (int c = 0; c < 64; c += 8)
            *(uint4*)(dstp + c) = *(const uint4*)(srcp + c);
    }
    __syncthreads();

    f32x4 pacc[4][4];
    #pragma unroll
    for (int rt = 0; rt < 4; rt++)
        #pragma unroll
        for (int c = 0; c < 4; c++) pacc[rt][c] = zero4;

    int prow[4];
    #pragma unroll
    for (int c = 0; c < 4; c++) prow[c] = (wv * 4 + c) * 16 + nn;  // output channel

    #pragma unroll
    for (int ks = 0; ks < 8; ks++) {
        bf16x8 a[4], b[4];
        #pragma unroll
        for (int rt = 0; rt < 4; rt++)
            a[rt] = *(const bf16x8*)(sX + (rt * 16 + nn) * 264 + ks * 32 + quad * 8);
        #pragma unroll
        for (int c = 0; c < 4; c++)
            b[c] = *(const bf16x8*)(Wp + (size_t)prow[c] * 256 + ks * 32 + quad * 8);
        #pragma unroll
        for (int rt = 0; rt < 4; rt++)
            #pragma unroll
            for (int c = 0; c < 4; c++)
                pacc[rt][c] = mfma_bf16(a[rt], b[c], pacc[rt][c]);
    }

    #pragma unroll
    for (int c = 0; c < 4; c++) {
        int chan = prow[c];
        float bias = bp[chan];
        #pragma unroll
        for (int rt = 0; rt < 4; rt++)
            #pragma unroll
            for (int r = 0; r < 4; r++) {
                int tok = rt * 16 + quad * 4 + r;
                int h = (wh * 8 + (tok >> 3) + shift) & 63;
                int w = (ww * 8 + (tok & 7) + shift) & 63;
                size_t idx = ((size_t)(bt * 4096 + h * 64 + w)) * 256 + chan;
                Xout[idx] = pacc[rt][c][r] + bias + Xin[idx];
            }
    }
}

// ---------------------------------------------------------------------------
extern "C" void kernel_launch(void* const* d_in, const int* in_sizes, int n_in,
                              void* d_out, int out_size, void* d_ws, size_t ws_size,
                              hipStream_t stream) {
    (void)in_sizes; (void)n_in; (void)out_size; (void)ws_size;

    const float* src        = (const float*)d_in[0];
    const float* a1_qkv_w   = (const float*)d_in[1];
    const float* a1_qkv_b   = (const float*)d_in[2];
    const float* a1_proj_w  = (const float*)d_in[3];
    const float* a1_proj_b  = (const float*)d_in[4];
    const float* a1_ls      = (const float*)d_in[5];
    const float* a1_w1      = (const float*)d_in[6];
    const float* a1_b1      = (const float*)d_in[7];
    const float* a1_w2      = (const float*)d_in[8];
    const float* a2_qkv_w   = (const float*)d_in[9];
    const float* a2_qkv_b   = (const float*)d_in[10];
    const float* a2_proj_w  = (const float*)d_in[11];
    const float* a2_proj_b  = (const float*)d_in[12];
    const float* a2_ls      = (const float*)d_in[13];
    const float* a2_w1      = (const float*)d_in[14];
    const float* a2_b1      = (const float*)d_in[15];
    const float* a2_w2      = (const float*)d_in[16];

    char* ws = (char*)d_ws;
    const size_t SZ_X = 134217728;  // 32*4096*256*4
    float* X0 = (float*)(ws);
    float* X1 = (float*)(ws + SZ_X);
    unsigned short* AO  = (unsigned short*)(ws + 2 * SZ_X);          // 67108864 B
    unsigned short* qw1 = (unsigned short*)(ws + 2 * SZ_X + 67108864);
    unsigned short* qw2 = qw1 + 196608;
    unsigned short* pw1 = qw2 + 196608;
    unsigned short* pw2 = pw1 + 65536;
    float* bt1 = (float*)(pw2 + 65536);
    float* bt2 = bt1 + 1800;

    k_setup<<<514, 256, 0, stream>>>(a1_qkv_w, a1_proj_w, a2_qkv_w, a2_proj_w,
                                     a1_w1, a1_b1, a1_w2, a2_w1, a2_b1, a2_w2,
                                     qw1, pw1, qw2, pw2, bt1, bt2);
    t_in<<<dim3(128, 8, 32), 256, 0, stream>>>(src, X0);

    // pass 1: no shift, no mask (attn+proj fused, per-window)
    k_swin<<<2048, 256, 0, stream>>>(X0, qw1, a1_qkv_b, a1_ls, bt1, pw1, a1_proj_b, AO, X1, 0, 0);
    // pass 2: shift 4, masked
    k_swin<<<2048, 256, 0, stream>>>(X1, qw2, a2_qkv_b, a2_ls, bt2, pw2, a2_proj_b, AO, X0, 4, 1);

    t_out<<<dim3(128, 8, 32), 256, 0, stream>>>(X0, (float*)d_out);
}